// Round 3
// baseline (623.317 us; speedup 1.0000x reference)
//
#include <hip/hip_runtime.h>

// KanvolutionLayer: out[b,o,hw] = (sum_{p,c} x^(p+1) Wp[p,o,c] + bp[o]) / (1 + |sum_{q,c} x^(q+1) Wq[q,o,c]|)
// MFMA GEMM, M=100352 (b*hw), K=1280 (p*256+c), N=512 (p/q outs interleaved per 16).
// R2 was LDS-pipe-bound (~95% sat, 4.8e7 bank-conflict cycles). R3: NO LDS, NO BARRIERS.
//  - A (x-powers) computed in registers directly in MFMA A-frag layout (lane owns m=col, c=quad*8+j).
//  - B (weights, 2.6MB hi+lo) loaded global->frags; L2-resident; 16x64B fully-used segments per load.
//  - bf16x2 3-product split (Ah*Bh + Al*Bh + Ah*Bl) with TRUNCATION split + v_perm packing
//    (lo captures hi's trunc error exactly; total rel err ~2^-16).
//  - p=0 chunk single-product (error share ~0.5); p=4 q-weights are zero -> skip odd-ni frags.

typedef __attribute__((ext_vector_type(8))) short bf16x8;           // MFMA A/B frag (4 VGPRs)
typedef __attribute__((ext_vector_type(4))) float f32x4;            // MFMA C/D frag

#define CIN    256
#define HW3    3136          // 56*56
#define MTOT   100352        // 32*3136 = 784 * 128
#define KTOT   1280
#define WPLANE (512 * 1280)

__device__ __forceinline__ unsigned short f2bf(float f) {
    union { float f; unsigned int u; } cv; cv.f = f;
    unsigned int u = cv.u;
    return (unsigned short)((u + 0x7FFFu + ((u >> 16) & 1u)) >> 16);  // RNE
}
__device__ __forceinline__ float bf2f(unsigned short h) {
    union { unsigned int u; float f; } cv; cv.u = ((unsigned int)h) << 16;
    return cv.f;
}

// Pack weights into bf16 hi/lo planes [512][1280]; row n -> (o,isq):
//   o = (n>>5)*16 + (n&15), isq = (n>>4)&1  (pairs P/Q frags per 16 cols). k = p*256 + c.
__global__ void pack_w_kernel(const float* __restrict__ Wp,
                              const float* __restrict__ Wq,
                              unsigned short* __restrict__ Whi,
                              unsigned short* __restrict__ Wlo) {
    int idx = blockIdx.x * 256 + threadIdx.x;      // [0, 512*1280)
    int n = idx / KTOT;
    int k = idx - n * KTOT;
    int p = k >> 8, c = k & 255;
    int o = ((n >> 5) << 4) + (n & 15);
    int isq = (n >> 4) & 1;
    float v;
    if (isq) v = (p < 4) ? Wq[((size_t)p * 256 + o) * 256 + c] : 0.0f;
    else     v = Wp[((size_t)p * 256 + o) * 256 + c];
    unsigned short h = f2bf(v);
    Whi[idx] = h;
    Wlo[idx] = f2bf(v - bf2f(h));   // exact residual, then one rounding
}

// Pack top-16 bits of 8 fp32 into a bf16x8 frag (truncation) via v_perm_b32.
__device__ __forceinline__ bf16x8 pack_hi8(const float* v) {
    const unsigned int* u = (const unsigned int*)v;
    union { unsigned int w[4]; bf16x8 h; } r;
    r.w[0] = __builtin_amdgcn_perm(u[1], u[0], 0x07060302);  // {v1.hi16, v0.hi16}
    r.w[1] = __builtin_amdgcn_perm(u[3], u[2], 0x07060302);
    r.w[2] = __builtin_amdgcn_perm(u[5], u[4], 0x07060302);
    r.w[3] = __builtin_amdgcn_perm(u[7], u[6], 0x07060302);
    return r.h;
}
__device__ __forceinline__ void resid8(const float* v, float* l) {
#pragma unroll
    for (int j = 0; j < 8; ++j) {
        union { unsigned int u; float f; } cv;
        cv.u = ((const unsigned int*)v)[j] & 0xFFFF0000u;    // hi as fp32 (exact)
        l[j] = v[j] - cv.f;                                  // exact residual
    }
}

__global__ __launch_bounds__(256, 2) void kanv_gemm(
    const float* __restrict__ x,
    const unsigned short* __restrict__ Whi,
    const unsigned short* __restrict__ Wlo,
    const float* __restrict__ bp,
    float* __restrict__ out)
{
    const int tid  = threadIdx.x;
    const int lane = tid & 63;
    const int wave = tid >> 6;
    const int wm   = wave >> 1;
    const int wn   = wave & 1;
    const int col  = lane & 15;
    const int quad = lane >> 4;

    const int nt = blockIdx.x & 3;     // n-tile (4 x 128 = 512)
    const int mt = blockIdx.x >> 2;    // m-tile (784 x 128)
    const int m0 = mt * 128 + wm * 64;

    // per-mi x base: lane holds A[m = m0+mi*16+col][c = g*32+quad*8+j]
    const float* xb[4];
#pragma unroll
    for (int mi = 0; mi < 4; ++mi) {
        int m  = m0 + mi * 16 + col;
        int bb = m / HW3, hw = m - bb * HW3;
        xb[mi] = x + ((size_t)bb * CIN) * HW3 + hw;
    }
    // per-ni W row base: lane holds B[n = nt*128+wn*64+ni*16+col][k = quad*8+j]
    const unsigned short *wh[4], *wl[4];
#pragma unroll
    for (int ni = 0; ni < 4; ++ni) {
        int n = nt * 128 + wn * 64 + ni * 16 + col;
        wh[ni] = Whi + (size_t)n * KTOT + quad * 8;
        wl[ni] = Wlo + (size_t)n * KTOT + quad * 8;
    }

    f32x4 acc[4][4];
#pragma unroll
    for (int mi = 0; mi < 4; ++mi)
#pragma unroll
        for (int ni = 0; ni < 4; ++ni)
            acc[mi][ni] = (f32x4){0.f, 0.f, 0.f, 0.f};

    float xv[4][8], pw[4][8];

    for (int g = 0; g < 8; ++g) {
        // x loads: coalesced 64B segments (16 lanes x consecutive hw), once per 32-ch group
#pragma unroll
        for (int mi = 0; mi < 4; ++mi) {
            const float* xp = xb[mi] + (size_t)(g * 32 + quad * 8) * HW3;
#pragma unroll
            for (int j = 0; j < 8; ++j) { xv[mi][j] = xp[(size_t)j * HW3]; pw[mi][j] = xv[mi][j]; }
        }

#pragma unroll
        for (int p = 0; p < 5; ++p) {
            // A frags from registers (truncation split; lo exact-captures hi error)
            bf16x8 ah[4], al[4];
#pragma unroll
            for (int mi = 0; mi < 4; ++mi) {
                ah[mi] = pack_hi8(pw[mi]);
                if (p > 0) {
                    float lo[8];
                    resid8(pw[mi], lo);
                    al[mi] = pack_hi8(lo);
                }
            }
            const int koff = p * 256 + g * 32;
#pragma unroll
            for (int ni = 0; ni < 4; ++ni) {
                if (p == 4 && (ni & 1)) continue;            // q-weights zero at p=4
                bf16x8 bh = *(const bf16x8*)(wh[ni] + koff);
#pragma unroll
                for (int mi = 0; mi < 4; ++mi)
                    acc[mi][ni] = __builtin_amdgcn_mfma_f32_16x16x32_bf16(ah[mi], bh, acc[mi][ni], 0, 0, 0);
                if (p > 0) {
                    bf16x8 bl = *(const bf16x8*)(wl[ni] + koff);
#pragma unroll
                    for (int mi = 0; mi < 4; ++mi) {
                        acc[mi][ni] = __builtin_amdgcn_mfma_f32_16x16x32_bf16(al[mi], bh, acc[mi][ni], 0, 0, 0);
                        acc[mi][ni] = __builtin_amdgcn_mfma_f32_16x16x32_bf16(ah[mi], bl, acc[mi][ni], 0, 0, 0);
                    }
                }
            }
            if (p < 4) {
#pragma unroll
                for (int mi = 0; mi < 4; ++mi)
#pragma unroll
                    for (int j = 0; j < 8; ++j) pw[mi][j] *= xv[mi][j];   // next power, fp32
            }
        }
    }

    // ---- epilogue (verified R2): pair (sum_p, sum_q) frags, bias, divide, float4 store ----
#pragma unroll
    for (int j = 0; j < 2; ++j) {
        const int o = (nt * 4 + wn * 2 + j) * 16 + col;
        const float bias = bp[o];
#pragma unroll
        for (int mi = 0; mi < 4; ++mi) {
            f32x4 sp = acc[mi][2 * j];
            f32x4 sq = acc[mi][2 * j + 1];
            const int mrow = m0 + mi * 16 + quad * 4;  // 4 consecutive hw, same image
            const int b2  = mrow / HW3;
            const int hw2 = mrow - b2 * HW3;
            float4 v;
            v.x = (sp[0] + bias) / (1.0f + fabsf(sq[0]));
            v.y = (sp[1] + bias) / (1.0f + fabsf(sq[1]));
            v.z = (sp[2] + bias) / (1.0f + fabsf(sq[2]));
            v.w = (sp[3] + bias) / (1.0f + fabsf(sq[3]));
            *(float4*)&out[((size_t)b2 * 256 + o) * HW3 + hw2] = v;
        }
    }
}

extern "C" void kernel_launch(void* const* d_in, const int* in_sizes, int n_in,
                              void* d_out, int out_size, void* d_ws, size_t ws_size,
                              hipStream_t stream) {
    const float* x  = (const float*)d_in[0];
    const float* Wp = (const float*)d_in[1];
    const float* bp = (const float*)d_in[2];
    const float* Wq = (const float*)d_in[3];
    float* out = (float*)d_out;
    unsigned short* Whi = (unsigned short*)d_ws;              // 1.31 MB
    unsigned short* Wlo = Whi + WPLANE;                        // +1.31 MB

    pack_w_kernel<<<WPLANE / 256, 256, 0, stream>>>(Wp, Wq, Whi, Wlo);
    kanv_gemm<<<(MTOT / 128) * 4, 256, 0, stream>>>(x, Whi, Wlo, bp, out);
}

// Round 4
// 507.596 us; speedup vs baseline: 1.2280x; 1.2280x over previous
//
#include <hip/hip_runtime.h>

// KanvolutionLayer: out[b,o,hw] = (sum_{p,c} x^(p+1) Wp[p,o,c] + bp[o]) / (1 + |sum_{q,c} x^(q+1) Wq[q,o,c]|)
// MFMA GEMM, M=100352 (b*hw), K=1280 (p*256+c), N=512 (p/q outs interleaved per 16).
// R2: LDS-pipe bound (A+B both through LDS, conflicts). R3: no LDS -> latency-bound (2 waves/SIMD,
// per-wave L2/HBM chains exposed; both pipes ~25%). R4 hybrid:
//  - A (x-powers) in registers, MFMA A-frag layout, trunc-split hi/lo (lo exact-captures hi error).
//  - B staged to LDS once per 32-ch group g via global_load_lds(16B): hi p0-4 + lo p1-3 = 64KB,
//    shared by all 4 waves; p4 lo (2 frags) direct from L2.
//  - 16B-granular swizzled LDS layout: phys = [n>>4][c4][n&15] -> DMA contiguous AND b128 frag
//    reads <=2-way per 16-lane phase.
//  - x for g+1 prefetched into regs right after the stage barrier (~1800 cyc cover).

typedef __attribute__((ext_vector_type(8))) short bf16x8;           // MFMA A/B frag (4 VGPRs)
typedef __attribute__((ext_vector_type(4))) float f32x4;            // MFMA C/D frag

#define CIN    256
#define HW3    3136          // 56*56
#define MTOT   100352        // 32*3136 = 784 * 128
#define KTOT   1280
#define WPLANE (512 * 1280)

__device__ __forceinline__ unsigned short f2bf(float f) {
    union { float f; unsigned int u; } cv; cv.f = f;
    unsigned int u = cv.u;
    return (unsigned short)((u + 0x7FFFu + ((u >> 16) & 1u)) >> 16);  // RNE
}
__device__ __forceinline__ float bf2f(unsigned short h) {
    union { unsigned int u; float f; } cv; cv.u = ((unsigned int)h) << 16;
    return cv.f;
}

// Pack weights into bf16 hi/lo planes [512][1280]; row n -> (o,isq):
//   o = (n>>5)*16 + (n&15), isq = (n>>4)&1  (pairs P/Q frags per 16 cols). k = p*256 + c.
__global__ void pack_w_kernel(const float* __restrict__ Wp,
                              const float* __restrict__ Wq,
                              unsigned short* __restrict__ Whi,
                              unsigned short* __restrict__ Wlo) {
    int idx = blockIdx.x * 256 + threadIdx.x;      // [0, 512*1280)
    int n = idx / KTOT;
    int k = idx - n * KTOT;
    int p = k >> 8, c = k & 255;
    int o = ((n >> 5) << 4) + (n & 15);
    int isq = (n >> 4) & 1;
    float v;
    if (isq) v = (p < 4) ? Wq[((size_t)p * 256 + o) * 256 + c] : 0.0f;
    else     v = Wp[((size_t)p * 256 + o) * 256 + c];
    unsigned short h = f2bf(v);
    Whi[idx] = h;
    Wlo[idx] = f2bf(v - bf2f(h));   // exact residual, then one rounding
}

// Pack top-16 bits of 8 fp32 into a bf16x8 frag (truncation) via v_perm_b32.
__device__ __forceinline__ bf16x8 pack_hi8(const float* v) {
    const unsigned int* u = (const unsigned int*)v;
    union { unsigned int w[4]; bf16x8 h; } r;
    r.w[0] = __builtin_amdgcn_perm(u[1], u[0], 0x07060302);
    r.w[1] = __builtin_amdgcn_perm(u[3], u[2], 0x07060302);
    r.w[2] = __builtin_amdgcn_perm(u[5], u[4], 0x07060302);
    r.w[3] = __builtin_amdgcn_perm(u[7], u[6], 0x07060302);
    return r.h;
}
__device__ __forceinline__ void resid8(const float* v, float* l) {
#pragma unroll
    for (int j = 0; j < 8; ++j) {
        union { unsigned int u; float f; } cv;
        cv.u = ((const unsigned int*)v)[j] & 0xFFFF0000u;    // hi as fp32 (exact)
        l[j] = v[j] - cv.f;                                  // exact residual
    }
}

__global__ __launch_bounds__(256, 2) void kanv_gemm(
    const float* __restrict__ x,
    const unsigned short* __restrict__ Whi,
    const unsigned short* __restrict__ Wlo,
    const float* __restrict__ bp,
    float* __restrict__ out)
{
    // 8 slabs x 8KB: s=0..4 -> hi plane p=s ; s=5..7 -> lo plane p=s-4. 64 KB total.
    __shared__ __align__(16) char sB[8 * 8192];

    const int tid  = threadIdx.x;
    const int lane = tid & 63;
    const int wave = tid >> 6;
    const int wm   = wave >> 1;
    const int wn   = wave & 1;
    const int col  = lane & 15;
    const int quad = lane >> 4;

    const int nt = blockIdx.x & 3;     // n-tile (4 x 128 = 512)
    const int mt = blockIdx.x >> 2;    // m-tile (784 x 128)
    const int m0 = mt * 128 + wm * 64;

    // per-mi x base: lane holds A[m = m0+mi*16+col][c = g*32+quad*8+j]
    const float* xb[4];
#pragma unroll
    for (int mi = 0; mi < 4; ++mi) {
        int m  = m0 + mi * 16 + col;
        int bb = m / HW3, hw = m - bb * HW3;
        xb[mi] = x + ((size_t)bb * CIN) * HW3 + hw;
    }
    // direct-from-L2 lo pointers, only used at p=4 (even ni)
    const unsigned short* wl4[2];
#pragma unroll
    for (int e = 0; e < 2; ++e) {
        int n = nt * 128 + wn * 64 + (2 * e) * 16 + col;
        wl4[e] = Wlo + (size_t)n * KTOT + quad * 8 + 4 * 256;
    }

    // ---- staging geometry ----
    // slab-local 16B-chunk t = i*64 + lane (i = wave + 4*ii, ii=0..1):
    //   n = i*16 + (lane&15), c4 = lane>>4 ; src = plane + (nt*128+n)*2560B + (p*256+g*32)*2B + c4*16B
    //   lds dst = sB + s*8192 + i*1024 + lane*16  (DMA: uniform base + lane*16)
    int voff[2];
#pragma unroll
    for (int ii = 0; ii < 2; ++ii) {
        int i = wave + 4 * ii;
        int n = i * 16 + col;
        voff[ii] = (nt * 128 + n) * 2560 + quad * 16;   // bytes
    }
    // frag-read base: addr = s*8192 + (wn*4+ni)*1024 + quad*256 + col*16
    const int rbase = (wn * 4) * 1024 + quad * 256 + col * 16;

    f32x4 acc[4][4];
#pragma unroll
    for (int mi = 0; mi < 4; ++mi)
#pragma unroll
        for (int ni = 0; ni < 4; ++ni)
            acc[mi][ni] = (f32x4){0.f, 0.f, 0.f, 0.f};

    float xv[4][8], pw[4][8], xn[4][8];

    // initial x load (g=0)
#pragma unroll
    for (int mi = 0; mi < 4; ++mi) {
        const float* xp = xb[mi] + (size_t)(quad * 8) * HW3;
#pragma unroll
        for (int j = 0; j < 8; ++j) { xv[mi][j] = xp[(size_t)j * HW3]; pw[mi][j] = xv[mi][j]; }
    }

    for (int g = 0; g < 8; ++g) {
        __syncthreads();   // prior g's sB reads complete before overwrite

        // ---- stage B slabs for this g (async DMA, 16 instr/wave) ----
#pragma unroll
        for (int s = 0; s < 8; ++s) {
            const unsigned short* plane = (s < 5) ? Whi : Wlo;
            const int p = (s < 5) ? s : (s - 4);
            const char* srcb = (const char*)plane + (size_t)((p * 256 + g * 32) * 2);
#pragma unroll
            for (int ii = 0; ii < 2; ++ii) {
                const int i = wave + 4 * ii;
                __builtin_amdgcn_global_load_lds(
                    (const __attribute__((address_space(1))) void*)(srcb + voff[ii]),
                    (__attribute__((address_space(3))) void*)(sB + s * 8192 + i * 1024),
                    16, 0, 0);
            }
        }
        __syncthreads();   // compiler drains vmcnt before barrier -> DMA visible to all waves

        // ---- prefetch x for g+1 (consumed ~5 chunks later) ----
        if (g < 7) {
#pragma unroll
            for (int mi = 0; mi < 4; ++mi) {
                const float* xp = xb[mi] + (size_t)((g + 1) * 32 + quad * 8) * HW3;
#pragma unroll
                for (int j = 0; j < 8; ++j) xn[mi][j] = xp[(size_t)j * HW3];
            }
        }

        // ---- compute 5 p-chunks from registers(A) + LDS(B) ----
#pragma unroll
        for (int p = 0; p < 5; ++p) {
            bf16x8 ah[4], al[4];
#pragma unroll
            for (int mi = 0; mi < 4; ++mi) {
                ah[mi] = pack_hi8(pw[mi]);
                if (p > 0) {
                    float lo[8];
                    resid8(pw[mi], lo);
                    al[mi] = pack_hi8(lo);
                }
            }
            const char* sb_p = sB + p * 8192 + rbase;
#pragma unroll
            for (int ni = 0; ni < 4; ++ni) {
                if (p == 4 && (ni & 1)) continue;            // q-weights zero at p=4
                bf16x8 bh = *(const bf16x8*)(sb_p + ni * 1024);
#pragma unroll
                for (int mi = 0; mi < 4; ++mi)
                    acc[mi][ni] = __builtin_amdgcn_mfma_f32_16x16x32_bf16(ah[mi], bh, acc[mi][ni], 0, 0, 0);
                if (p > 0) {
                    bf16x8 bl;
                    if (p < 4) bl = *(const bf16x8*)(sB + (p + 4) * 8192 + rbase + ni * 1024);
                    else       bl = *(const bf16x8*)(wl4[ni >> 1] + g * 32);
#pragma unroll
                    for (int mi = 0; mi < 4; ++mi) {
                        acc[mi][ni] = __builtin_amdgcn_mfma_f32_16x16x32_bf16(al[mi], bh, acc[mi][ni], 0, 0, 0);
                        acc[mi][ni] = __builtin_amdgcn_mfma_f32_16x16x32_bf16(ah[mi], bl, acc[mi][ni], 0, 0, 0);
                    }
                }
            }
            if (p < 4) {
#pragma unroll
                for (int mi = 0; mi < 4; ++mi)
#pragma unroll
                    for (int j = 0; j < 8; ++j) pw[mi][j] *= xv[mi][j];   // next power, fp32
            }
        }

        if (g < 7) {
#pragma unroll
            for (int mi = 0; mi < 4; ++mi)
#pragma unroll
                for (int j = 0; j < 8; ++j) { xv[mi][j] = xn[mi][j]; pw[mi][j] = xn[mi][j]; }
        }
    }

    // ---- epilogue (verified R2/R3): pair (sum_p, sum_q) frags, bias, divide, float4 store ----
#pragma unroll
    for (int j = 0; j < 2; ++j) {
        const int o = (nt * 4 + wn * 2 + j) * 16 + col;
        const float bias = bp[o];
#pragma unroll
        for (int mi = 0; mi < 4; ++mi) {
            f32x4 sp = acc[mi][2 * j];
            f32x4 sq = acc[mi][2 * j + 1];
            const int mrow = m0 + mi * 16 + quad * 4;  // 4 consecutive hw, same image
            const int b2  = mrow / HW3;
            const int hw2 = mrow - b2 * HW3;
            float4 v;
            v.x = (sp[0] + bias) / (1.0f + fabsf(sq[0]));
            v.y = (sp[1] + bias) / (1.0f + fabsf(sq[1]));
            v.z = (sp[2] + bias) / (1.0f + fabsf(sq[2]));
            v.w = (sp[3] + bias) / (1.0f + fabsf(sq[3]));
            *(float4*)&out[((size_t)b2 * 256 + o) * HW3 + hw2] = v;
        }
    }
}

extern "C" void kernel_launch(void* const* d_in, const int* in_sizes, int n_in,
                              void* d_out, int out_size, void* d_ws, size_t ws_size,
                              hipStream_t stream) {
    const float* x  = (const float*)d_in[0];
    const float* Wp = (const float*)d_in[1];
    const float* bp = (const float*)d_in[2];
    const float* Wq = (const float*)d_in[3];
    float* out = (float*)d_out;
    unsigned short* Whi = (unsigned short*)d_ws;              // 1.31 MB
    unsigned short* Wlo = Whi + WPLANE;                        // +1.31 MB

    pack_w_kernel<<<WPLANE / 256, 256, 0, stream>>>(Wp, Wq, Whi, Wlo);
    kanv_gemm<<<(MTOT / 128) * 4, 256, 0, stream>>>(x, Whi, Wlo, bp, out);
}